// Round 8
// baseline (1054.603 us; speedup 1.0000x reference)
//
#include <hip/hip_runtime.h>
#include <stdint.h>

#define C_ 128
#define G  4    // independent sample-groups per block (latency interleave)

typedef __attribute__((ext_vector_type(8))) short short8;
typedef __attribute__((ext_vector_type(4))) float f32x4;
typedef __attribute__((ext_vector_type(4))) unsigned int u32x4;

__device__ __forceinline__ unsigned short f2bf(float x){
  unsigned u = __builtin_bit_cast(unsigned, x);
  return (unsigned short)((u + 0x7FFFu + ((u >> 16) & 1u)) >> 16);
}
__device__ __forceinline__ float bf2f(unsigned short h){
  unsigned u = ((unsigned)h) << 16;
  return __builtin_bit_cast(float, u);
}
__device__ __forceinline__ unsigned cvtpk(float lo, float hi){
  unsigned r;
  asm("v_cvt_pk_bf16_f32 %0, %1, %2" : "=v"(r) : "v"(lo), "v"(hi));
  return r;
}
__device__ __forceinline__ void bar(){
  asm volatile("s_waitcnt lgkmcnt(0)" ::: "memory");
  __builtin_amdgcn_s_barrier();
  asm volatile("" ::: "memory");
}

// mask dtype probe: lengths >= L/2 >= 4, so first 4 mask elems are true.
__device__ __forceinline__ bool mask_is_i32(const void* mask){
  return ((const unsigned*)mask)[0] == 1u;
}

// ---------------- path-score kernel ----------------
__global__ __launch_bounds__(256) void crf_sent(
    const float* __restrict__ logits,
    const float* __restrict__ trans,
    const int*   __restrict__ labels,
    const void*  __restrict__ mask,
    int L,
    const int* __restrict__ startp, const int* __restrict__ endp,
    float* __restrict__ sent)
{
  const int n = blockIdx.x;
  const int tid = threadIdx.x;
  const int start_tag = *startp;
  const int end_tag   = *endp;
  const bool i32m = mask_is_i32(mask);
  const int*  lab  = labels + (size_t)n * L;
  const int*           m32 = (const int*)mask + (size_t)n * L;
  const unsigned char* m8  = (const unsigned char*)mask + (size_t)n * L;
  const float* lrow = logits + (size_t)n * L * C_;

  float s = 0.f;
  for (int t = tid; t < L; t += 256) {
    int mt = i32m ? m32[t] : (int)m8[t];
    if (mt) {
      int lt  = lab[t];
      int mn  = (t + 1 < L) ? (i32m ? m32[t + 1] : (int)m8[t + 1]) : 0;
      int nxt = mn ? lab[t + 1] : end_tag;
      s += lrow[(size_t)t * C_ + lt] + trans[(size_t)nxt * C_ + lt];
    }
  }
  if (tid == 0) s += trans[(size_t)lab[0] * C_ + start_tag];

  for (int m = 1; m < 64; m <<= 1) s += __shfl_xor(s, m, 64);
  __shared__ float red[4];
  if ((tid & 63) == 0) red[tid >> 6] = s;
  __syncthreads();
  if (tid == 0) sent[n] = (red[0] + red[1]) + (red[2] + red[3]);
}

// ---------------- 8-wave j-split scan, G=4 interleaved groups, 64 samples/block ------
// Wave w owns tags [16w,16w+16). Per sample row: 16 chunks of 16B, phys = logical ^ lj.
// k-map (A and B identical): k(ks,lg,e) = 32ks + 8lg + e.
__global__ __launch_bounds__(512, 1) void crf_scan(
    const float* __restrict__ logits,
    const float* __restrict__ trans,
    const void*  __restrict__ mask,
    const float* __restrict__ sent,
    float* __restrict__ out,
    int L,
    const int* __restrict__ startp, const int* __restrict__ endp)
{
  __shared__ unsigned st[G * 2 * 1024];   // per group: double-buffered 4KB state
  __shared__ float mred[G * 16 * 8];

  const int tid = threadIdx.x;
  const int w   = tid >> 6;     // wave: tags [16w,16w+16)
  const int l   = tid & 63;
  const int lj  = l & 15;       // sample-within-group
  const int lg  = l >> 4;       // 0..3
  const int j0  = 16 * w + 4 * lg;
  const int n0  = blockIdx.x * (16 * G);
  const int start_tag = *startp;
  const int end_tag   = *endp;
  const bool i32m = mask_is_i32(mask);
  const float L2E = 1.44269504088896340736f;
  const float NC  = -8.0f * L2E;
  const float LN2 = 0.69314718055994530942f;

  // ---- lengths for each group's sample lj ----
  int len_g[G];
  #pragma unroll
  for (int g = 0; g < G; g++) {
    int cnt = 0;
    const int seg = L >> 2;
    if (i32m) {
      const int4* m4 = (const int4*)((const int*)mask + (size_t)(n0 + 16 * g + lj) * L + lg * seg);
      for (int i = 0; i < (seg >> 2); i++) {
        int4 v = m4[i];
        cnt += (v.x != 0) + (v.y != 0) + (v.z != 0) + (v.w != 0);
      }
    } else {
      const unsigned* mr = (const unsigned*)((const unsigned char*)mask + (size_t)(n0 + 16 * g + lj) * L + lg * seg);
      for (int i = 0; i < (seg >> 2); i++) cnt += __popc(mr[i]);
    }
    cnt += __shfl_xor(cnt, 16);
    cnt += __shfl_xor(cnt, 32);
    len_g[g] = cnt;
  }
  int mn = len_g[0];
  #pragma unroll
  for (int g = 1; g < G; g++) mn = min(mn, len_g[g]);
  mn = min(mn, __shfl_xor(mn, 1));
  mn = min(mn, __shfl_xor(mn, 2));
  mn = min(mn, __shfl_xor(mn, 4));
  mn = min(mn, __shfl_xor(mn, 8));
  const int T_main = (mn - 2) & ~1;

  // ---- A-frags (shared by all groups): E^T rows [16w,16w+16) ----
  short8 af[4];
  #pragma unroll
  for (int ks = 0; ks < 4; ks++) {
    const float* tp = trans + (size_t)(16 * w + lj) * C_ + 32 * ks + 8 * lg;
    f32x4 e0 = *(const f32x4*)tp;
    f32x4 e1 = *(const f32x4*)(tp + 4);
    short8 f;
    #pragma unroll
    for (int i = 0; i < 4; i++) f[i] = (short)f2bf(expf(e0[i]));
    #pragma unroll
    for (int i = 0; i < 4; i++) f[4 + i] = (short)f2bf(expf(e1[i]));
    af[ks] = f;
  }

  // ---- init state buffers ----
  #pragma unroll
  for (int k = 0; k < (G * 2 * 1024) / (4 * 512); k++)
    ((u32x4*)st)[tid + k * 512] = (u32x4){0, 0, 0, 0};
  bar();
  if (tid < 16) {
    int phys = ((start_tag >> 3) ^ tid) & 15;
    unsigned val = (start_tag & 1) ? 0x3F800000u : 0x00003F80u;
    #pragma unroll
    for (int g = 0; g < G; g++)
      st[(g * 2 + 0) * 1024 + tid * 64 + phys * 4 + ((start_tag & 7) >> 1)] = val;
  }
  bar();

  unsigned pv0[G], pv1[G];
  {
    unsigned a = 0, b = 0;
    #pragma unroll
    for (int i = 0; i < 4; i++)
      if (j0 + i == start_tag) {
        if (i == 0) a |= 0x3F80u;
        if (i == 1) a |= 0x3F80u << 16;
        if (i == 2) b |= 0x3F80u;
        if (i == 3) b |= 0x3F80u << 16;
      }
    #pragma unroll
    for (int g = 0; g < G; g++) { pv0[g] = a; pv1[g] = b; }
  }

  // ---- LDS offsets (u32 units), 16B-chunk XOR swizzle ----
  const int wr_off = lj * 64 + ((((2 * w + (lg >> 1)) ^ lj) & 15) << 2) + ((lg & 1) << 1);
  const int rd0 = lj * 64 + ((((0  + lg) ^ lj) & 15) << 2);
  const int rd1 = lj * 64 + ((((4  + lg) ^ lj) & 15) << 2);
  const int rd2 = lj * 64 + ((((8  + lg) ^ lj) & 15) << 2);
  const int rd3 = lj * 64 + ((((12 + lg) ^ lj) & 15) << 2);

  // ---- per-group logits bases; prologue loads for t=0 then t=1 ----
  const float* lbase[G];
  #pragma unroll
  for (int g = 0; g < G; g++)
    lbase[g] = logits + (size_t)(n0 + 16 * g + lj) * L * C_ + j0;

  f32x4 lv[G][2];
  #pragma unroll
  for (int g = 0; g < G; g++)
    asm volatile("global_load_dwordx4 %0, %1, off" : "=v"(lv[g][0]) : "v"(lbase[g]));
  #pragma unroll
  for (int g = 0; g < G; g++)
    asm volatile("global_load_dwordx4 %0, %1, off" : "=v"(lv[g][1]) : "v"(lbase[g] + C_));

  float lm[G];
  #pragma unroll
  for (int g = 0; g < G; g++) lm[g] = 0.f;

#define SCAN_STEP(T, SLOT, TAILF)                                              \
  {                                                                            \
    const int CUR = (T) & 1;                                                   \
    asm volatile("s_waitcnt vmcnt(4)" ::: "memory");                           \
    __builtin_amdgcn_sched_barrier(0);                                         \
    float p[G][4];                                                             \
    _Pragma("unroll") for (int g = 0; g < G; g++)                              \
      _Pragma("unroll") for (int i = 0; i < 4; i++)                            \
        p[g][i] = __builtin_amdgcn_exp2f(fmaf(lv[g][SLOT][i], L2E, NC));       \
    {                                                                          \
      int ts = (TAILF) ? min((T) + 2, L - 1) : ((T) + 2);                      \
      _Pragma("unroll") for (int g = 0; g < G; g++) {                          \
        const float* lp = lbase[g] + (size_t)ts * C_;                          \
        asm volatile("global_load_dwordx4 %0, %1, off"                         \
                     : "=v"(lv[g][SLOT]) : "v"(lp));                           \
      }                                                                        \
    }                                                                          \
    float wv[G][4];                                                            \
    _Pragma("unroll") for (int g = 0; g < G; g++) {                            \
      const unsigned* sc = st + (g * 2 + CUR) * 1024;                          \
      u32x4 b0 = *(const u32x4*)&sc[rd0];                                      \
      u32x4 b1 = *(const u32x4*)&sc[rd1];                                      \
      u32x4 b2 = *(const u32x4*)&sc[rd2];                                      \
      u32x4 b3 = *(const u32x4*)&sc[rd3];                                      \
      f32x4 z = {0.f, 0.f, 0.f, 0.f};                                          \
      f32x4 a1 = __builtin_amdgcn_mfma_f32_16x16x32_bf16(af[0], __builtin_bit_cast(short8, b0), z, 0, 0, 0); \
      a1 = __builtin_amdgcn_mfma_f32_16x16x32_bf16(af[1], __builtin_bit_cast(short8, b1), a1, 0, 0, 0);      \
      f32x4 a2 = __builtin_amdgcn_mfma_f32_16x16x32_bf16(af[2], __builtin_bit_cast(short8, b2), z, 0, 0, 0); \
      a2 = __builtin_amdgcn_mfma_f32_16x16x32_bf16(af[3], __builtin_bit_cast(short8, b3), a2, 0, 0, 0);      \
      _Pragma("unroll") for (int i = 0; i < 4; i++)                            \
        wv[g][i] = (a1[i] + a2[i]) * p[g][i];                                  \
    }                                                                          \
    if (((T) & 7) == 7) {                                                      \
      _Pragma("unroll") for (int g = 0; g < G; g++) {                          \
        float tm = fmaxf(fmaxf(wv[g][0], wv[g][1]), fmaxf(wv[g][2], wv[g][3]));\
        tm = fmaxf(tm, __shfl_xor(tm, 16));                                    \
        tm = fmaxf(tm, __shfl_xor(tm, 32));                                    \
        if (lg == 0) mred[g * 128 + lj * 8 + w] = tm;                          \
      }                                                                        \
      bar();                                                                   \
      _Pragma("unroll") for (int g = 0; g < G; g++) {                          \
        f32x4 ma = *(const f32x4*)&mred[g * 128 + lj * 8];                     \
        f32x4 mb = *(const f32x4*)&mred[g * 128 + lj * 8 + 4];                 \
        float m = fmaxf(fmaxf(fmaxf(ma[0], ma[1]), fmaxf(ma[2], ma[3])),       \
                        fmaxf(fmaxf(mb[0], mb[1]), fmaxf(mb[2], mb[3])));      \
        float rm = __builtin_amdgcn_rcpf(m);                                   \
        _Pragma("unroll") for (int i = 0; i < 4; i++) wv[g][i] *= rm;          \
        if (!(TAILF) || (T) < len_g[g]) lm[g] += LN2 * __builtin_amdgcn_logf(m); \
      }                                                                        \
    }                                                                          \
    _Pragma("unroll") for (int g = 0; g < G; g++) {                            \
      unsigned k0 = cvtpk(wv[g][0], wv[g][1]);                                 \
      unsigned k1 = cvtpk(wv[g][2], wv[g][3]);                                 \
      if (TAILF) {                                                             \
        bool alive = (T) < len_g[g];                                           \
        k0 = alive ? k0 : pv0[g];                                              \
        k1 = alive ? k1 : pv1[g];                                              \
      }                                                                        \
      *(unsigned long long*)&st[(g * 2 + (CUR ^ 1)) * 1024 + wr_off] =         \
          ((unsigned long long)k1 << 32) | k0;                                 \
      pv0[g] = k0; pv1[g] = k1;                                                \
    }                                                                          \
    bar();                                                                     \
  }

  for (int t = 0; t < T_main; t += 2) {
    SCAN_STEP(t,     0, false);
    SCAN_STEP(t + 1, 1, false);
  }
  for (int t = T_main; t < L; t += 2) {
    SCAN_STEP(t,     0, true);
    SCAN_STEP(t + 1, 1, true);
  }
#undef SCAN_STEP

  // ---- epilogue ----
  {
    const float* te = trans + (size_t)end_tag * C_ + j0;
    float e0 = expf(te[0]), e1 = expf(te[1]), e2 = expf(te[2]), e3 = expf(te[3]);
    #pragma unroll
    for (int g = 0; g < G; g++) {
      float es = bf2f((unsigned short)(pv0[g] & 0xffff)) * e0
               + bf2f((unsigned short)(pv0[g] >> 16))    * e1
               + bf2f((unsigned short)(pv1[g] & 0xffff)) * e2
               + bf2f((unsigned short)(pv1[g] >> 16))    * e3;
      es += __shfl_xor(es, 16);
      es += __shfl_xor(es, 32);
      if (lg == 0) mred[g * 128 + lj * 8 + w] = es;
    }
    bar();
    if (w == 0 && lg == 0) {
      #pragma unroll
      for (int g = 0; g < G; g++) {
        f32x4 a = *(const f32x4*)&mred[g * 128 + lj * 8];
        f32x4 b = *(const f32x4*)&mred[g * 128 + lj * 8 + 4];
        float S = ((a[0] + a[1]) + (a[2] + a[3])) + ((b[0] + b[1]) + (b[2] + b[3]));
        float total = 8.0f * (float)len_g[g] + lm[g] + LN2 * __builtin_amdgcn_logf(S);
        out[n0 + 16 * g + lj] = total - sent[n0 + 16 * g + lj];
      }
    }
  }
}

extern "C" void kernel_launch(void* const* d_in, const int* in_sizes, int n_in,
                              void* d_out, int out_size, void* d_ws, size_t ws_size,
                              hipStream_t stream) {
  const float* logits = (const float*)d_in[0];
  const float* trans  = (const float*)d_in[1];
  const int*   labels = (const int*)d_in[2];
  const void*  mask   = (const void*)d_in[3];
  const int* startp = (const int*)d_in[4];
  const int* endp   = (const int*)d_in[5];
  float* out  = (float*)d_out;
  float* sent = (float*)d_ws;

  const int N = out_size;            // 512
  const int L = in_sizes[2] / N;     // 1024

  crf_sent<<<N, 256, 0, stream>>>(logits, trans, labels, mask, L, startp, endp, sent);
  crf_scan<<<N / (16 * G), 512, 0, stream>>>(logits, trans, mask, sent, out, L, startp, endp);
}

// Round 9
// 393.597 us; speedup vs baseline: 2.6794x; 2.6794x over previous
//
#include <hip/hip_runtime.h>
#include <stdint.h>

#define C_ 128

typedef __attribute__((ext_vector_type(8))) short short8;
typedef __attribute__((ext_vector_type(4))) float f32x4;
typedef __attribute__((ext_vector_type(4))) unsigned int u32x4;

__device__ __forceinline__ unsigned short f2bf(float x){
  unsigned u = __builtin_bit_cast(unsigned, x);
  return (unsigned short)((u + 0x7FFFu + ((u >> 16) & 1u)) >> 16);
}
__device__ __forceinline__ float bf2f(unsigned short h){
  unsigned u = ((unsigned)h) << 16;
  return __builtin_bit_cast(float, u);
}
__device__ __forceinline__ unsigned cvtpk(float lo, float hi){
  unsigned r;
  asm("v_cvt_pk_bf16_f32 %0, %1, %2" : "=v"(r) : "v"(lo), "v"(hi));
  return r;
}
__device__ __forceinline__ void bar(){
  asm volatile("s_waitcnt lgkmcnt(0)" ::: "memory");
  __builtin_amdgcn_s_barrier();
  asm volatile("" ::: "memory");
}

// mask dtype probe: lengths >= L/2 >= 4, so first 4 mask elems are true.
__device__ __forceinline__ bool mask_is_i32(const void* mask){
  return ((const unsigned*)mask)[0] == 1u;
}

// ---------------- path-score kernel ----------------
__global__ __launch_bounds__(256) void crf_sent(
    const float* __restrict__ logits,
    const float* __restrict__ trans,
    const int*   __restrict__ labels,
    const void*  __restrict__ mask,
    int L,
    const int* __restrict__ startp, const int* __restrict__ endp,
    float* __restrict__ sent)
{
  const int n = blockIdx.x;
  const int tid = threadIdx.x;
  const int start_tag = *startp;
  const int end_tag   = *endp;
  const bool i32m = mask_is_i32(mask);
  const int*  lab  = labels + (size_t)n * L;
  const int*           m32 = (const int*)mask + (size_t)n * L;
  const unsigned char* m8  = (const unsigned char*)mask + (size_t)n * L;
  const float* lrow = logits + (size_t)n * L * C_;

  float s = 0.f;
  for (int t = tid; t < L; t += 256) {
    int mt = i32m ? m32[t] : (int)m8[t];
    if (mt) {
      int lt  = lab[t];
      int mn  = (t + 1 < L) ? (i32m ? m32[t + 1] : (int)m8[t + 1]) : 0;
      int nxt = mn ? lab[t + 1] : end_tag;
      s += lrow[(size_t)t * C_ + lt] + trans[(size_t)nxt * C_ + lt];
    }
  }
  if (tid == 0) s += trans[(size_t)lab[0] * C_ + start_tag];

  for (int m = 1; m < 64; m <<= 1) s += __shfl_xor(s, m, 64);
  __shared__ float red[4];
  if ((tid & 63) == 0) red[tid >> 6] = s;
  __syncthreads();
  if (tid == 0) sent[n] = (red[0] + red[1]) + (red[2] + red[3]);
}

// ---------------- 4-wave j-split scan: 16 samples / 256-thread block, 32 blocks ------
// Wave w owns tags j in [32w, 32w+32) as TWO 16x16 MFMA j-tiles sharing ONE state read.
// Lane (w,lg,lj): outputs j = 32w+8lg+{0..7}  (jmap(q, 4lg+i) = 32w+8lg+4q+i)
// k-map (A and B identical): k(ks,lg,e) = 32ks+8lg+e.
// State LDS row (per sample): 16 chunks x 16B, phys chunk = logical ^ lj (bijective).
// Lazy renorm: local max written at t==7 (mod 8), folded into S at t==0 (mod 8) after
// the regular end-of-step barrier -- exactly one barrier per step.
__global__ __launch_bounds__(256, 1) void crf_scan(
    const float* __restrict__ logits,
    const float* __restrict__ trans,
    const void*  __restrict__ mask,
    const float* __restrict__ sent,
    float* __restrict__ out,
    int L,
    const int* __restrict__ startp, const int* __restrict__ endp)
{
  __shared__ unsigned st[2 * 1024];    // double-buffered state, 8 KB
  __shared__ float mred[64];           // [lj][w] partial maxes / epilogue sums

  const int tid = threadIdx.x;
  const int w   = tid >> 6;     // wave 0..3: tags [32w, 32w+32)
  const int l   = tid & 63;
  const int lj  = l & 15;       // sample within block
  const int lg  = l >> 4;       // 0..3
  const int j0r = 32 * w + 8 * lg;   // lane's first output tag
  const int n0  = blockIdx.x * 16;
  const int start_tag = *startp;
  const int end_tag   = *endp;
  const bool i32m = mask_is_i32(mask);
  const float L2E = 1.44269504088896340736f;
  const float NC  = -8.0f * L2E;
  const float LN2 = 0.69314718055994530942f;

  // ---- length of sample lj ----
  int cnt = 0;
  {
    const int seg = L >> 2;
    if (i32m) {
      const int4* m4 = (const int4*)((const int*)mask + (size_t)(n0 + lj) * L + lg * seg);
      for (int i = 0; i < (seg >> 2); i++) {
        int4 v = m4[i];
        cnt += (v.x != 0) + (v.y != 0) + (v.z != 0) + (v.w != 0);
      }
    } else {
      const unsigned* mr = (const unsigned*)((const unsigned char*)mask + (size_t)(n0 + lj) * L + lg * seg);
      for (int i = 0; i < (seg >> 2); i++) cnt += __popc(mr[i]);
    }
    cnt += __shfl_xor(cnt, 16);
    cnt += __shfl_xor(cnt, 32);
  }
  const int len_n = cnt;
  int mn = len_n;
  mn = min(mn, __shfl_xor(mn, 1));
  mn = min(mn, __shfl_xor(mn, 2));
  mn = min(mn, __shfl_xor(mn, 4));
  mn = min(mn, __shfl_xor(mn, 8));
  const int T_main = (mn - 2) & ~1;

  // ---- A-frags: af[q][ks], row r=4lg'+i -> j = 32w + 8*(r>>2) + 4q + (r&3) ----
  short8 af[2][4];
  #pragma unroll
  for (int q = 0; q < 2; q++) {
    #pragma unroll
    for (int ks = 0; ks < 4; ks++) {
      int row = 32 * w + 8 * (lj >> 2) + 4 * q + (lj & 3);
      const float* tp = trans + (size_t)row * C_ + 32 * ks + 8 * lg;
      f32x4 e0 = *(const f32x4*)tp;
      f32x4 e1 = *(const f32x4*)(tp + 4);
      short8 f;
      #pragma unroll
      for (int i = 0; i < 4; i++) f[i] = (short)f2bf(expf(e0[i]));
      #pragma unroll
      for (int i = 0; i < 4; i++) f[4 + i] = (short)f2bf(expf(e1[i]));
      af[q][ks] = f;
    }
  }

  // ---- init: zero st, set start_tag in st[0], prime mred with 1.0 ----
  #pragma unroll
  for (int k = 0; k < 2; k++)
    ((u32x4*)st)[tid + k * 256] = (u32x4){0, 0, 0, 0};
  if (tid < 64) mred[tid] = 1.0f;
  bar();
  if (tid < 16) {
    int phys = ((start_tag >> 3) ^ tid) & 15;
    st[tid * 64 + phys * 4 + ((start_tag & 7) >> 1)] =
        (start_tag & 1) ? 0x3F800000u : 0x00003F80u;
  }
  bar();

  // prev-state (for tail freeze): lane's own 8 tags
  u32x4 pvv = {0, 0, 0, 0};
  #pragma unroll
  for (int i = 0; i < 8; i++)
    if (j0r + i == start_tag)
      pvv[i >> 1] |= 0x3F80u << (16 * (i & 1));

  // ---- LDS word offsets (16B-chunk XOR swizzle) ----
  const int wr_off = lj * 64 + ((((4 * w  + lg) ^ lj) & 15) << 2);
  const int rd0    = lj * 64 + ((((0      + lg) ^ lj) & 15) << 2);
  const int rd1    = lj * 64 + ((((4      + lg) ^ lj) & 15) << 2);
  const int rd2    = lj * 64 + ((((8      + lg) ^ lj) & 15) << 2);
  const int rd3    = lj * 64 + ((((12     + lg) ^ lj) & 15) << 2);

  // ---- logits: lane loads its own 8 tags [n0+lj][t][j0r..j0r+7] (2x dwordx4) ----
  const float* lbase = logits + (size_t)(n0 + lj) * L * C_ + j0r;
  f32x4 lv[2][2];
  asm volatile("global_load_dwordx4 %0, %1, off" : "=v"(lv[0][0]) : "v"(lbase));
  asm volatile("global_load_dwordx4 %0, %1, off" : "=v"(lv[0][1]) : "v"(lbase + 4));
  asm volatile("global_load_dwordx4 %0, %1, off" : "=v"(lv[1][0]) : "v"(lbase + C_));
  asm volatile("global_load_dwordx4 %0, %1, off" : "=v"(lv[1][1]) : "v"(lbase + C_ + 4));

  float lm = 0.f;

#define SCAN_STEP(T, SLOT, TAILF)                                                \
  {                                                                              \
    const int CUR = (T) & 1;                                                     \
    asm volatile("s_waitcnt vmcnt(2)" ::: "memory");                             \
    __builtin_amdgcn_sched_barrier(0);                                           \
    float pq[2][4];                                                              \
    _Pragma("unroll") for (int q = 0; q < 2; q++)                                \
      _Pragma("unroll") for (int i = 0; i < 4; i++)                              \
        pq[q][i] = __builtin_amdgcn_exp2f(fmaf(lv[SLOT][q][i], L2E, NC));        \
    {                                                                            \
      int ts = (TAILF) ? min((T) + 2, L - 1) : ((T) + 2);                        \
      const float* lp = lbase + (size_t)ts * C_;                                 \
      asm volatile("global_load_dwordx4 %0, %1, off" : "=v"(lv[SLOT][0]) : "v"(lp));     \
      asm volatile("global_load_dwordx4 %0, %1, off" : "=v"(lv[SLOT][1]) : "v"(lp + 4)); \
    }                                                                            \
    const unsigned* sc = st + CUR * 1024;                                        \
    u32x4 b0 = *(const u32x4*)&sc[rd0];                                          \
    u32x4 b1 = *(const u32x4*)&sc[rd1];                                          \
    u32x4 b2 = *(const u32x4*)&sc[rd2];                                          \
    u32x4 b3 = *(const u32x4*)&sc[rd3];                                          \
    float wv[2][4];                                                              \
    _Pragma("unroll") for (int q = 0; q < 2; q++) {                              \
      f32x4 z = {0.f, 0.f, 0.f, 0.f};                                            \
      f32x4 a1 = __builtin_amdgcn_mfma_f32_16x16x32_bf16(af[q][0], __builtin_bit_cast(short8, b0), z, 0, 0, 0); \
      a1 = __builtin_amdgcn_mfma_f32_16x16x32_bf16(af[q][1], __builtin_bit_cast(short8, b1), a1, 0, 0, 0);      \
      f32x4 a2 = __builtin_amdgcn_mfma_f32_16x16x32_bf16(af[q][2], __builtin_bit_cast(short8, b2), z, 0, 0, 0); \
      a2 = __builtin_amdgcn_mfma_f32_16x16x32_bf16(af[q][3], __builtin_bit_cast(short8, b3), a2, 0, 0, 0);      \
      _Pragma("unroll") for (int i = 0; i < 4; i++)                              \
        wv[q][i] = (a1[i] + a2[i]) * pq[q][i];                                   \
    }                                                                            \
    if (((T) & 7) == 0) { /* lazy-apply renorm published at step T-1 */          \
      f32x4 mr = *(const f32x4*)&mred[lj * 4];                                   \
      float m = fmaxf(fmaxf(mr[0], mr[1]), fmaxf(mr[2], mr[3]));                 \
      float rm = __builtin_amdgcn_rcpf(m);                                       \
      _Pragma("unroll") for (int q = 0; q < 2; q++)                              \
        _Pragma("unroll") for (int i = 0; i < 4; i++) wv[q][i] *= rm;            \
      if (!(TAILF) || (T) < len_n) lm += LN2 * __builtin_amdgcn_logf(m);         \
    }                                                                            \
    if (((T) & 7) == 7) { /* compute local max; published by this step's bar */  \
      float tm = wv[0][0];                                                       \
      _Pragma("unroll") for (int q = 0; q < 2; q++)                              \
        _Pragma("unroll") for (int i = 0; i < 4; i++) tm = fmaxf(tm, wv[q][i]);  \
      tm = fmaxf(tm, __shfl_xor(tm, 16));                                        \
      tm = fmaxf(tm, __shfl_xor(tm, 32));                                        \
      if (lg == 0) mred[lj * 4 + w] = tm;                                        \
    }                                                                            \
    u32x4 nv;                                                                    \
    nv[0] = cvtpk(wv[0][0], wv[0][1]);                                           \
    nv[1] = cvtpk(wv[0][2], wv[0][3]);                                           \
    nv[2] = cvtpk(wv[1][0], wv[1][1]);                                           \
    nv[3] = cvtpk(wv[1][2], wv[1][3]);                                           \
    if (TAILF) {                                                                 \
      bool alive = (T) < len_n;                                                  \
      _Pragma("unroll") for (int i = 0; i < 4; i++)                              \
        nv[i] = alive ? nv[i] : pvv[i];                                          \
    }                                                                            \
    *(u32x4*)&st[(CUR ^ 1) * 1024 + wr_off] = nv;                                \
    pvv = nv;                                                                    \
    bar();                                                                       \
  }

  for (int t = 0; t < T_main; t += 2) {
    SCAN_STEP(t,     0, false);
    SCAN_STEP(t + 1, 1, false);
  }
  for (int t = T_main; t < L; t += 2) {
    SCAN_STEP(t,     0, true);
    SCAN_STEP(t + 1, 1, true);
  }
#undef SCAN_STEP

  // ---- epilogue: out[n] = 8*len + lm + ln(sum_j A_j * exp(T[end,j])) - sent[n] ----
  // (any renorm still pending cancels exactly: state unscaled <-> lm missing log m)
  {
    const float* te = trans + (size_t)end_tag * C_ + j0r;
    float es = 0.f;
    #pragma unroll
    for (int i = 0; i < 8; i++) {
      unsigned u = pvv[i >> 1];
      unsigned short h = (unsigned short)((i & 1) ? (u >> 16) : (u & 0xffff));
      es += bf2f(h) * expf(te[i]);
    }
    es += __shfl_xor(es, 16);
    es += __shfl_xor(es, 32);
    if (lg == 0) mred[lj * 4 + w] = es;
    bar();
    if (w == 0 && lg == 0) {
      f32x4 a = *(const f32x4*)&mred[lj * 4];
      float S = (a[0] + a[1]) + (a[2] + a[3]);
      float total = 8.0f * (float)len_n + lm + LN2 * __builtin_amdgcn_logf(S);
      out[n0 + lj] = total - sent[n0 + lj];
    }
  }
}

extern "C" void kernel_launch(void* const* d_in, const int* in_sizes, int n_in,
                              void* d_out, int out_size, void* d_ws, size_t ws_size,
                              hipStream_t stream) {
  const float* logits = (const float*)d_in[0];
  const float* trans  = (const float*)d_in[1];
  const int*   labels = (const int*)d_in[2];
  const void*  mask   = (const void*)d_in[3];
  const int* startp = (const int*)d_in[4];
  const int* endp   = (const int*)d_in[5];
  float* out  = (float*)d_out;
  float* sent = (float*)d_ws;

  const int N = out_size;            // 512
  const int L = in_sizes[2] / N;     // 1024

  crf_sent<<<N, 256, 0, stream>>>(logits, trans, labels, mask, L, startp, endp, sent);
  crf_scan<<<N / 16, 256, 0, stream>>>(logits, trans, mask, sent, out, L, startp, endp);
}

// Round 12
// 358.541 us; speedup vs baseline: 2.9414x; 1.0978x over previous
//
#include <hip/hip_runtime.h>
#include <stdint.h>

#define C_ 128

typedef __attribute__((ext_vector_type(8))) short short8;
typedef __attribute__((ext_vector_type(4))) float f32x4;
typedef __attribute__((ext_vector_type(4))) unsigned int u32x4;

__device__ __forceinline__ unsigned short f2bf(float x){
  unsigned u = __builtin_bit_cast(unsigned, x);
  return (unsigned short)((u + 0x7FFFu + ((u >> 16) & 1u)) >> 16);
}
__device__ __forceinline__ float bf2f(unsigned short h){
  unsigned u = ((unsigned)h) << 16;
  return __builtin_bit_cast(float, u);
}
__device__ __forceinline__ unsigned cvtpk(float lo, float hi){
  unsigned r;
  asm("v_cvt_pk_bf16_f32 %0, %1, %2" : "=v"(r) : "v"(lo), "v"(hi));
  return r;
}
__device__ __forceinline__ void bar(){
  asm volatile("s_waitcnt lgkmcnt(0)" ::: "memory");
  __builtin_amdgcn_s_barrier();
  asm volatile("" ::: "memory");
}

// mask dtype probe: lengths >= L/2 >= 4, so first 4 mask elems are true.
__device__ __forceinline__ bool mask_is_i32(const void* mask){
  return ((const unsigned*)mask)[0] == 1u;
}

// ---------------- path-score kernel ----------------
__global__ __launch_bounds__(256) void crf_sent(
    const float* __restrict__ logits,
    const float* __restrict__ trans,
    const int*   __restrict__ labels,
    const void*  __restrict__ mask,
    int L,
    const int* __restrict__ startp, const int* __restrict__ endp,
    float* __restrict__ sent)
{
  const int n = blockIdx.x;
  const int tid = threadIdx.x;
  const int start_tag = *startp;
  const int end_tag   = *endp;
  const bool i32m = mask_is_i32(mask);
  const int*  lab  = labels + (size_t)n * L;
  const int*           m32 = (const int*)mask + (size_t)n * L;
  const unsigned char* m8  = (const unsigned char*)mask + (size_t)n * L;
  const float* lrow = logits + (size_t)n * L * C_;

  float s = 0.f;
  for (int t = tid; t < L; t += 256) {
    int mt = i32m ? m32[t] : (int)m8[t];
    if (mt) {
      int lt  = lab[t];
      int mn  = (t + 1 < L) ? (i32m ? m32[t + 1] : (int)m8[t + 1]) : 0;
      int nxt = mn ? lab[t + 1] : end_tag;
      s += lrow[(size_t)t * C_ + lt] + trans[(size_t)nxt * C_ + lt];
    }
  }
  if (tid == 0) s += trans[(size_t)lab[0] * C_ + start_tag];

  for (int m = 1; m < 64; m <<= 1) s += __shfl_xor(s, m, 64);
  __shared__ float red[4];
  if ((tid & 63) == 0) red[tid >> 6] = s;
  __syncthreads();
  if (tid == 0) sent[n] = (red[0] + red[1]) + (red[2] + red[3]);
}

// ---------------- 8-wave j-split scan: 16 samples / 512-thread block, 32 blocks ------
// Identical to the round-7 kernel (passed, 355 us) except ONE change: the state
// ds_reads (b0-b3) are issued at the top of the step, BEFORE the vmcnt wait, so the
// ~320cy LDS drain overlaps the logits-load wait + exp2 block. Eager renorm (2 bars
// on renorm steps) kept verbatim — lazy renorm is blacklisted at 8 waves (r10/r11).
__global__ __launch_bounds__(512, 1) void crf_scan(
    const float* __restrict__ logits,
    const float* __restrict__ trans,
    const void*  __restrict__ mask,
    const float* __restrict__ sent,
    float* __restrict__ out,
    int L,
    const int* __restrict__ startp, const int* __restrict__ endp)
{
  __shared__ unsigned st[2 * 1024];   // 8 KB state, double-buffered, chunk-swizzled
  __shared__ float mred[16][8];

  const int tid = threadIdx.x;
  const int w   = tid >> 6;     // wave 0..7: owns tags [16w,16w+16)
  const int l   = tid & 63;
  const int lj  = l & 15;       // sample within block
  const int lg  = l >> 4;       // 0..3
  const int j0  = 16 * w + 4 * lg;
  const int n0  = blockIdx.x * 16;
  const int start_tag = *startp;
  const int end_tag   = *endp;
  const bool i32m = mask_is_i32(mask);
  const float LN2 = 0.69314718055994530942f;

  // ---- length of sample lj (each wave redundantly) ----
  int cnt = 0;
  {
    const int seg = L >> 2;
    if (i32m) {
      const int4* m4 = (const int4*)((const int*)mask + (size_t)(n0 + lj) * L + lg * seg);
      for (int i = 0; i < (seg >> 2); i++) {
        int4 v = m4[i];
        cnt += (v.x != 0) + (v.y != 0) + (v.z != 0) + (v.w != 0);
      }
    } else {
      const unsigned* mr = (const unsigned*)((const unsigned char*)mask + (size_t)(n0 + lj) * L + lg * seg);
      for (int i = 0; i < (seg >> 2); i++) cnt += __popc(mr[i]);
    }
    cnt += __shfl_xor(cnt, 16);
    cnt += __shfl_xor(cnt, 32);
  }
  const int len_n = cnt;
  int mn = len_n;
  mn = min(mn, __shfl_xor(mn, 1));
  mn = min(mn, __shfl_xor(mn, 2));
  mn = min(mn, __shfl_xor(mn, 4));
  mn = min(mn, __shfl_xor(mn, 8));
  const int T_main = (mn - 2) & ~1;

  // ---- A-frags: E^T rows [16w,16w+16), natural k-map k=32ks+8lg+e ----
  short8 af[4];
  #pragma unroll
  for (int ks = 0; ks < 4; ks++) {
    const float* tp = trans + (size_t)(16 * w + lj) * C_ + 32 * ks + 8 * lg;
    f32x4 e0 = *(const f32x4*)tp;
    f32x4 e1 = *(const f32x4*)(tp + 4);
    short8 f;
    #pragma unroll
    for (int i = 0; i < 4; i++) f[i] = (short)f2bf(expf(e0[i]));
    #pragma unroll
    for (int i = 0; i < 4; i++) f[4 + i] = (short)f2bf(expf(e1[i]));
    af[ks] = f;
  }

  // ---- init state: zeros + 1.0 at start_tag, in st[0] ----
  ((u32x4*)st)[tid] = (u32x4){0, 0, 0, 0};
  bar();
  if (tid < 16) {
    int phys = ((start_tag >> 3) ^ tid) & 15;
    st[tid * 64 + phys * 4 + ((start_tag & 7) >> 1)] =
        (start_tag & 1) ? 0x3F800000u : 0x00003F80u;
  }
  bar();

  unsigned prev0 = 0, prev1 = 0;
  #pragma unroll
  for (int i = 0; i < 4; i++)
    if (j0 + i == start_tag) {
      if (i == 0) prev0 |= 0x3F80u;
      if (i == 1) prev0 |= 0x3F80u << 16;
      if (i == 2) prev1 |= 0x3F80u;
      if (i == 3) prev1 |= 0x3F80u << 16;
    }

  // ---- LDS offsets (u32 units), 16B-chunk XOR swizzle: phys = logical ^ lj ----
  const int wr_off = lj * 64 + ((((2 * w + (lg >> 1)) ^ lj) & 15) << 2) + ((lg & 1) << 1);
  const int rd0 = lj * 64 + ((((0 + lg) ^ lj) & 15) << 2);
  const int rd1 = lj * 64 + ((((4 + lg) ^ lj) & 15) << 2);
  const int rd2 = lj * 64 + ((((8 + lg) ^ lj) & 15) << 2);
  const int rd3 = lj * 64 + ((((12 + lg) ^ lj) & 15) << 2);

  // ---- logits: lane loads its own 4 tags: [n0+lj][t][j0..j0+3] ----
  const float* lbase = logits + (size_t)(n0 + lj) * L * C_ + j0;
  f32x4 lvA, lvB;
  asm volatile("global_load_dwordx4 %0, %1, off" : "=v"(lvA) : "v"(lbase));
  asm volatile("global_load_dwordx4 %0, %1, off" : "=v"(lvB) : "v"(lbase + C_));

  const float L2E = 1.44269504088896340736f;
  const float NC  = -8.0f * L2E;
  float lm = 0.f;

#define SCAN_STEP(T, LV, CUR, TAILF)                                              \
  {                                                                               \
    /* HOIST: state reads issued first — LDS drain overlaps vmcnt wait + exp2 */  \
    const unsigned* sc = st + (CUR) * 1024;                                       \
    u32x4 b0 = *(const u32x4*)&sc[rd0];                                           \
    u32x4 b1 = *(const u32x4*)&sc[rd1];                                           \
    u32x4 b2 = *(const u32x4*)&sc[rd2];                                           \
    u32x4 b3 = *(const u32x4*)&sc[rd3];                                           \
    asm volatile("s_waitcnt vmcnt(1)" ::: "memory");                              \
    __builtin_amdgcn_sched_barrier(0);                                            \
    float p0 = __builtin_amdgcn_exp2f(fmaf(LV[0], L2E, NC));                      \
    float p1 = __builtin_amdgcn_exp2f(fmaf(LV[1], L2E, NC));                      \
    float p2 = __builtin_amdgcn_exp2f(fmaf(LV[2], L2E, NC));                      \
    float p3 = __builtin_amdgcn_exp2f(fmaf(LV[3], L2E, NC));                      \
    {                                                                             \
      int ts = TAILF ? min((T) + 2, L - 1) : ((T) + 2);                           \
      const float* lp = lbase + (size_t)ts * C_;                                  \
      asm volatile("global_load_dwordx4 %0, %1, off" : "=v"(LV) : "v"(lp));       \
    }                                                                             \
    f32x4 z = {0.f, 0.f, 0.f, 0.f};                                               \
    f32x4 acc = __builtin_amdgcn_mfma_f32_16x16x32_bf16(af[0], __builtin_bit_cast(short8, b0), z, 0, 0, 0); \
    acc = __builtin_amdgcn_mfma_f32_16x16x32_bf16(af[1], __builtin_bit_cast(short8, b1), acc, 0, 0, 0);     \
    f32x4 ac2 = __builtin_amdgcn_mfma_f32_16x16x32_bf16(af[2], __builtin_bit_cast(short8, b2), z, 0, 0, 0); \
    ac2 = __builtin_amdgcn_mfma_f32_16x16x32_bf16(af[3], __builtin_bit_cast(short8, b3), ac2, 0, 0, 0);     \
    float wv0 = (acc[0] + ac2[0]) * p0;                                           \
    float wv1 = (acc[1] + ac2[1]) * p1;                                           \
    float wv2 = (acc[2] + ac2[2]) * p2;                                           \
    float wv3 = (acc[3] + ac2[3]) * p3;                                           \
    if (((T) & 7) == 7) {                                                         \
      float tm = fmaxf(fmaxf(wv0, wv1), fmaxf(wv2, wv3));                         \
      tm = fmaxf(tm, __shfl_xor(tm, 16));                                         \
      tm = fmaxf(tm, __shfl_xor(tm, 32));                                         \
      if (lg == 0) mred[lj][w] = tm;                                              \
      bar();                                                                      \
      f32x4 ma = *(const f32x4*)&mred[lj][0];                                     \
      f32x4 mb = *(const f32x4*)&mred[lj][4];                                     \
      float m = fmaxf(fmaxf(fmaxf(ma[0], ma[1]), fmaxf(ma[2], ma[3])),            \
                      fmaxf(fmaxf(mb[0], mb[1]), fmaxf(mb[2], mb[3])));           \
      float rm = __builtin_amdgcn_rcpf(m);                                        \
      wv0 *= rm; wv1 *= rm; wv2 *= rm; wv3 *= rm;                                 \
      if (!(TAILF) || (T) < len_n) lm += LN2 * __builtin_amdgcn_logf(m);          \
    }                                                                             \
    unsigned pk0 = cvtpk(wv0, wv1);                                               \
    unsigned pk1 = cvtpk(wv2, wv3);                                               \
    if (TAILF) {                                                                  \
      bool alive = (T) < len_n;                                                   \
      pk0 = alive ? pk0 : prev0;                                                  \
      pk1 = alive ? pk1 : prev1;                                                  \
    }                                                                             \
    *(unsigned long long*)&st[((CUR) ^ 1) * 1024 + wr_off] =                      \
        ((unsigned long long)pk1 << 32) | pk0;                                    \
    prev0 = pk0; prev1 = pk1;                                                     \
    bar();                                                                        \
  }

  for (int t = 0; t < T_main; t += 2) {
    SCAN_STEP(t,     lvA, 0, false);
    SCAN_STEP(t + 1, lvB, 1, false);
  }
  for (int t = T_main; t < L; t += 2) {
    SCAN_STEP(t,     lvA, 0, true);
    SCAN_STEP(t + 1, lvB, 1, true);
  }
#undef SCAN_STEP

  // ---- epilogue: per-lane 4-tag partial of sum_j A_j * exp(T[end,j]) ----
  {
    const float* te = trans + (size_t)end_tag * C_ + j0;
    float es = bf2f((unsigned short)(prev0 & 0xffff)) * expf(te[0])
             + bf2f((unsigned short)(prev0 >> 16))    * expf(te[1])
             + bf2f((unsigned short)(prev1 & 0xffff)) * expf(te[2])
             + bf2f((unsigned short)(prev1 >> 16))    * expf(te[3]);
    es += __shfl_xor(es, 16);
    es += __shfl_xor(es, 32);
    if (lg == 0) mred[lj][w] = es;
    bar();
    if (w == 0 && lg == 0) {
      f32x4 a = *(const f32x4*)&mred[lj][0];
      f32x4 b = *(const f32x4*)&mred[lj][4];
      float S = ((a[0] + a[1]) + (a[2] + a[3])) + ((b[0] + b[1]) + (b[2] + b[3]));
      float total = 8.0f * (float)len_n + lm + LN2 * __builtin_amdgcn_logf(S);
      out[n0 + lj] = total - sent[n0 + lj];
    }
  }
}

extern "C" void kernel_launch(void* const* d_in, const int* in_sizes, int n_in,
                              void* d_out, int out_size, void* d_ws, size_t ws_size,
                              hipStream_t stream) {
  const float* logits = (const float*)d_in[0];
  const float* trans  = (const float*)d_in[1];
  const int*   labels = (const int*)d_in[2];
  const void*  mask   = (const void*)d_in[3];
  const int* startp = (const int*)d_in[4];
  const int* endp   = (const int*)d_in[5];
  float* out  = (float*)d_out;
  float* sent = (float*)d_ws;

  const int N = out_size;            // 512
  const int L = in_sizes[2] / N;     // 1024

  crf_sent<<<N, 256, 0, stream>>>(logits, trans, labels, mask, L, startp, endp, sent);
  crf_scan<<<N / 16, 512, 0, stream>>>(logits, trans, mask, sent, out, L, startp, endp);
}